// Round 13
// baseline (182.764 us; speedup 1.0000x reference)
//
#include <hip/hip_runtime.h>
#include <cstdint>
#include <cstddef>

#define N_NODES 100000
#define N_EDGES 1600000

#define BKB   7                            // bucket = 128 nodes
#define BN    128
#define NBK   782                          // ceil(100000/128)
#define NPB   256                          // partition / hist blocks
#define EPB   ((N_EDGES + NPB - 1) / NPB)  // 6250 edges per block
#define NSLOT (NBK * NPB)                  // 200192 (bucket-major: slot = b*NPB + bid)
#define NSB   ((NSLOT + 1023) / 1024)      // 196 scan blocks
#define ES_CAP (N_EDGES + NBK * 1024 + 64) // padded edge-list capacity
#define EB_CAP 2560                        // LDS stage cap per bucket
#define GEMM1_BLOCKS ((N_NODES + 63) / 64) // 1563

typedef __attribute__((ext_vector_type(8))) short bf16x8;
typedef __attribute__((ext_vector_type(4))) float f32x4;

__device__ __forceinline__ float b2f(unsigned short u) {
    return __uint_as_float(((unsigned)u) << 16);
}
__device__ __forceinline__ unsigned short f2b(float f) {
    unsigned x = __float_as_uint(f);
    return (unsigned short)((x + 0x7FFFu + ((x >> 16) & 1u)) >> 16);
}

// split 8 f32 -> bf16 hi (trunc) + bf16 lo (trunc of exact residual)
__device__ __forceinline__ void split8a(const float* f, bf16x8& hi, bf16x8& lo) {
#pragma unroll
    for (int j = 0; j < 8; ++j) {
        unsigned u = __float_as_uint(f[j]);
        hi[j] = (short)(u >> 16);
        float l = f[j] - __uint_as_float(u & 0xFFFF0000u);   // exact
        lo[j] = (short)(__float_as_uint(l) >> 16);
    }
}
__device__ __forceinline__ void split8v(f32x4 a0, f32x4 a1, bf16x8& hi, bf16x8& lo) {
    float f[8] = {a0[0], a0[1], a0[2], a0[3], a1[0], a1[1], a1[2], a1[3]};
    split8a(f, hi, lo);
}

// 256-wide exclusive prefix of bsum[0..NSB) into pe[256]; call with all 256 threads
__device__ __forceinline__ void bsum_excl(const int* __restrict__ bsum, int* pe) {
    int t = threadIdx.x;
    int v = (t < NSB) ? bsum[t] : 0;
    pe[t] = v;
    __syncthreads();
    for (int o = 1; o < 256; o <<= 1) {
        int a = (t >= o) ? pe[t - o] : 0;
        __syncthreads();
        pe[t] += a;
        __syncthreads();
    }
    pe[t] -= v;   // exclusive
    __syncthreads();
}

// ---------------- K1: hist (blocks 0..NPB-1)  ||  gemm1-raw (blocks NPB..) ------------
// Independent work co-scheduled in one grid: hist's atomic latency hides under gemm1.
// gemm1 writes RAW bf16(x @ w1) (no dinv prescale -> no build dependency).

__global__ __launch_bounds__(256) void k_hist_gemm1(const int* __restrict__ dst,
                                                    int* __restrict__ gcnt,
                                                    const float* __restrict__ x,
                                                    const float* __restrict__ w,
                                                    unsigned short* __restrict__ hwb1,
                                                    unsigned short* __restrict__ hwb2,
                                                    float* __restrict__ dinv, int M) {
    __shared__ unsigned short Bhi[32 * 64 * 8];   // 32 KB (hist aliases as int lh[])
    __shared__ unsigned short Blo[32 * 64 * 8];   // 32 KB
    int t = threadIdx.x, bid = blockIdx.x;

    if (bid < NPB) {
        // ---- histogram role ----
        int* lh = (int*)Bhi;
        if (bid == 0) {
            if (t < 64) hwb1[(size_t)N_NODES * 64 + t] = 0;
            else if (t < 96) hwb2[(size_t)N_NODES * 32 + (t - 64)] = 0;
            else if (t == 96) dinv[N_NODES] = 0.0f;    // sentinel weight
        }
        for (int i = t; i < NBK; i += 256) lh[i] = 0;
        __syncthreads();
        int e0 = bid * EPB, e1 = min(N_EDGES, e0 + EPB);
        for (int e = e0 + t; e < e1; e += 256) atomicAdd(&lh[dst[e] >> BKB], 1);
        __syncthreads();
        for (int b = t; b < NBK; b += 256) gcnt[b * NPB + bid] = lh[b];
        return;
    }

    // ---- gemm1 role ----
    int tile = bid - NPB;
    int wave = t >> 6, lane = t & 63;
    {
        int c = t & 63;
        int kg0 = t >> 6;
#pragma unroll
        for (int i = 0; i < 8; ++i) {
            int kgrp = kg0 + i * 4;
            bf16x8 h8, l8;
#pragma unroll
            for (int j = 0; j < 8; ++j) {
                float f = w[(size_t)(kgrp * 8 + j) * 64 + c];
                unsigned u = __float_as_uint(f);
                h8[j] = (short)(u >> 16);
                float l = f - __uint_as_float(u & 0xFFFF0000u);
                l8[j] = (short)(__float_as_uint(l) >> 16);
            }
            *(bf16x8*)&Bhi[(kgrp * 64 + c) * 8] = h8;
            *(bf16x8*)&Blo[(kgrp * 64 + c) * 8] = l8;
        }
    }
    __syncthreads();

    int row0w = tile * 64 + wave * 16;
    int r = row0w + (lane & 15); if (r >= M) r = M - 1;
    const float* xr = x + (size_t)r * 256 + (lane >> 4) * 8;

    f32x4 acc[4] = {{0.f,0.f,0.f,0.f},{0.f,0.f,0.f,0.f},{0.f,0.f,0.f,0.f},{0.f,0.f,0.f,0.f}};

#pragma unroll
    for (int kf = 0; kf < 8; ++kf) {
        // non-temporal: x is read-once; keep L2 for hwb1/build structures
        f32x4 a0 = __builtin_nontemporal_load((const f32x4*)(xr + kf * 32));
        f32x4 a1 = __builtin_nontemporal_load((const f32x4*)(xr + kf * 32 + 4));
        bf16x8 ahi, alo;
        split8v(a0, a1, ahi, alo);
        int kgrpR = kf * 4 + (lane >> 4);
#pragma unroll
        for (int cf = 0; cf < 4; ++cf) {
            bf16x8 bhi = *(const bf16x8*)&Bhi[(kgrpR * 64 + cf * 16 + (lane & 15)) * 8];
            bf16x8 blo = *(const bf16x8*)&Blo[(kgrpR * 64 + cf * 16 + (lane & 15)) * 8];
            acc[cf] = __builtin_amdgcn_mfma_f32_16x16x32_bf16(ahi, bhi, acc[cf], 0, 0, 0);
            acc[cf] = __builtin_amdgcn_mfma_f32_16x16x32_bf16(ahi, blo, acc[cf], 0, 0, 0);
            acc[cf] = __builtin_amdgcn_mfma_f32_16x16x32_bf16(alo, bhi, acc[cf], 0, 0, 0);
        }
    }

#pragma unroll
    for (int j = 0; j < 4; ++j) {
        int rr = row0w + (lane >> 4) * 4 + j;
        if (rr < M) {
#pragma unroll
            for (int cf = 0; cf < 4; ++cf)
                hwb1[(size_t)rr * 64 + cf * 16 + (lane & 15)] = f2b(acc[cf][j]);
        }
    }
}

// per-scan-block local exclusive scan; bsum[blk] = block total
__global__ __launch_bounds__(1024) void k_scanA(int* __restrict__ g,
                                                int* __restrict__ bsum, int ntot) {
    __shared__ int s[1024];
    int t = threadIdx.x;
    int i = blockIdx.x * 1024 + t;
    int v = (i < ntot) ? g[i] : 0;
    s[t] = v;
    __syncthreads();
    for (int o = 1; o < 1024; o <<= 1) {
        int a = (t >= o) ? s[t - o] : 0;
        __syncthreads();
        s[t] += a;
        __syncthreads();
    }
    if (i < ntot) g[i] = s[t] - v;
    if (t == 1023) bsum[blockIdx.x] = s[1023];
}

__global__ __launch_bounds__(256) void k_partition(const int* __restrict__ src,
                                                   const int* __restrict__ dst,
                                                   const int* __restrict__ g,
                                                   const int* __restrict__ bsum,
                                                   unsigned* __restrict__ ebuf, int E) {
    __shared__ int lcur[NBK];
    __shared__ int pe[256];
    int t = threadIdx.x, bid = blockIdx.x;
    bsum_excl(bsum, pe);
    for (int b = t; b < NBK; b += 256) {
        int slot = b * NPB + bid;
        lcur[b] = g[slot] + pe[slot >> 10];
    }
    __syncthreads();
    int e0 = bid * EPB, e1 = min(E, e0 + EPB);
    for (int e = e0 + t; e < e1; e += 256) {
        int d = dst[e];
        int b = d >> BKB;
        int p = atomicAdd(&lcur[b], 1);
        ebuf[p] = (unsigned)src[e] | ((unsigned)(d & (BN - 1)) << 20);
    }
}

// one block per 128-node bucket: stage edges in LDS, count/scan/place -> 8-padded CSR
__global__ __launch_bounds__(256) void k_bucket_csr(const int* __restrict__ g,
                                                    const int* __restrict__ bsum,
                                                    const unsigned* __restrict__ ebuf,
                                                    int* __restrict__ cnt,
                                                    float* __restrict__ dinv,
                                                    int* __restrict__ off,
                                                    int* __restrict__ es, int n) {
    __shared__ unsigned eb[EB_CAP];
    __shared__ int lc[BN];
    __shared__ int ss[BN];
    __shared__ int lo[BN];
    __shared__ int lcur[BN];
    __shared__ int pe[256];
    int b = blockIdx.x, t = threadIdx.x;
    bsum_excl(bsum, pe);
    int s0 = b * NPB;
    int rstart = g[s0] + pe[s0 >> 10];
    int rend;
    if (b == NBK - 1) rend = N_EDGES;
    else { int s1 = (b + 1) * NPB; rend = g[s1] + pe[s1 >> 10]; }
    int m = rend - rstart;
    int ms = min(m, EB_CAP);
    int wstart = ((rstart + 7) & ~7) + b * 1024;   // 8-aligned private write region
    if (t < BN) lc[t] = 0;
    for (int i = t; i < ms; i += 256) eb[i] = ebuf[rstart + i];
    __syncthreads();
    for (int e = t; e < m; e += 256) {
        unsigned u = (e < ms) ? eb[e] : ebuf[rstart + e];
        atomicAdd(&lc[(int)(u >> 20)], 1);
    }
    __syncthreads();
    int v = 0, vp = 0;
    if (t < BN) {
        v = lc[t];               // real degree
        vp = (v + 7) & ~7;       // padded to multiple of 8
        ss[t] = vp;
    }
    __syncthreads();
    for (int o = 1; o < BN; o <<= 1) {
        int a = (t >= o && t < BN) ? ss[t - o] : 0;
        __syncthreads();
        if (t < BN) ss[t] += a;
        __syncthreads();
    }
    if (t < BN) {
        lo[t] = ss[t] - vp;
        lcur[t] = 0;
        int node = b * BN + t;
        if (node < n) {
            cnt[node] = vp;
            dinv[node] = rsqrtf((float)v + 1.0f);
            off[node] = wstart + lo[t];
        }
    }
    __syncthreads();
    for (int e = t; e < m; e += 256) {
        unsigned u = (e < ms) ? eb[e] : ebuf[rstart + e];
        int l = (int)(u >> 20);
        int p = atomicAdd(&lcur[l], 1);
        es[wstart + lo[l] + p] = (int)(u & 0xFFFFFu);
    }
    if (t < BN)
        for (int q = v; q < vp; ++q) es[wstart + lo[t] + q] = N_NODES;
}

// ---------------- fused agg1 + GEMM2: hwb2 = bf16( dinv * (relu-agg(hwb1raw) @ w2) ) --
// block = 16 nodes (4 waves x 4 interleaved nodes). Gather: lane = channel, 2B gathers,
// per-edge dinv[s] (wave-uniform L2-hit load). MFMA: waves 0/1, 16x32, hi/lo split.

__global__ __launch_bounds__(256) void k_agg1_gemm2(const unsigned short* __restrict__ hwb,
                                                    const float* __restrict__ dinv,
                                                    const int* __restrict__ cnt,
                                                    const int* __restrict__ off,
                                                    const int* __restrict__ es,
                                                    const float* __restrict__ bias,
                                                    const float* __restrict__ w2,
                                                    unsigned short* __restrict__ out) {
    __shared__ float hs[16][68];     // 16 h1 rows, padded (stride 68 -> 2-way banks)
    int t = threadIdx.x;
    int wv = t >> 6, lane = t & 63;
    int node0 = blockIdx.x * 16;
    float bl = bias[lane];

    float dn[4], a0[4], a1[4];
    const int* ep[4];
    int mp[4];
#pragma unroll
    for (int i = 0; i < 4; ++i) {
        int node = node0 + wv * 4 + i;
        dn[i] = dinv[node];
        a0[i] = dn[i] * b2f(hwb[(size_t)node * 64 + lane]);   // self: dn*raw (x dn later)
        a1[i] = 0.0f;
        ep[i] = es + off[node];
        mp[i] = cnt[node];
    }
    int mmax = max(max(mp[0], mp[1]), max(mp[2], mp[3]));
    for (int j = 0; j < mmax; j += 8) {
#pragma unroll
        for (int i = 0; i < 4; ++i) {
            if (j < mp[i]) {   // wave-uniform
                int4 e0 = *(const int4*)&ep[i][j];
                int4 e1 = *(const int4*)&ep[i][j + 4];
                float w0 = dinv[e0.x], w1 = dinv[e0.y], w2v = dinv[e0.z], w3 = dinv[e0.w];
                float w4 = dinv[e1.x], w5 = dinv[e1.y], w6 = dinv[e1.z], w7 = dinv[e1.w];
                float v0 = b2f(hwb[(size_t)e0.x * 64 + lane]);
                float v1 = b2f(hwb[(size_t)e0.y * 64 + lane]);
                float v2 = b2f(hwb[(size_t)e0.z * 64 + lane]);
                float v3 = b2f(hwb[(size_t)e0.w * 64 + lane]);
                float v4 = b2f(hwb[(size_t)e1.x * 64 + lane]);
                float v5 = b2f(hwb[(size_t)e1.y * 64 + lane]);
                float v6 = b2f(hwb[(size_t)e1.z * 64 + lane]);
                float v7 = b2f(hwb[(size_t)e1.w * 64 + lane]);
                a0[i] += (w0 * v0 + w1 * v1) + (w2v * v2 + w3 * v3);
                a1[i] += (w4 * v4 + w5 * v5) + (w6 * v6 + w7 * v7);
            }
        }
    }
#pragma unroll
    for (int i = 0; i < 4; ++i)
        hs[wv * 4 + i][lane] = fmaxf(fmaf(dn[i], a0[i] + a1[i], bl), 0.0f);
    __syncthreads();

    if (wv < 2) {
        int colbase = wv * 16;
        int r = lane & 15;           // A row / B col / C col
        int kg = lane >> 4;          // k-group 0..3
        f32x4 acc = {0.f, 0.f, 0.f, 0.f};
#pragma unroll
        for (int ks = 0; ks < 2; ++ks) {
            float a[8], b[8];
#pragma unroll
            for (int j = 0; j < 8; ++j) {
                int k = ks * 32 + kg * 8 + j;
                a[j] = hs[r][k];
                b[j] = w2[(size_t)k * 32 + colbase + r];
            }
            bf16x8 ahi, alo, bhi, blo;
            split8a(a, ahi, alo);
            split8a(b, bhi, blo);
            acc = __builtin_amdgcn_mfma_f32_16x16x32_bf16(ahi, bhi, acc, 0, 0, 0);
            acc = __builtin_amdgcn_mfma_f32_16x16x32_bf16(ahi, blo, acc, 0, 0, 0);
            acc = __builtin_amdgcn_mfma_f32_16x16x32_bf16(alo, bhi, acc, 0, 0, 0);
        }
#pragma unroll
        for (int reg = 0; reg < 4; ++reg) {
            int row = kg * 4 + reg;
            int nd = node0 + row;
            out[(size_t)nd * 32 + colbase + r] = f2b(acc[reg] * dinv[nd]);
        }
    }
}

// ---------------- agg layer 2 + fused MLP head ------------------

__global__ __launch_bounds__(256) void k_agg2_mlp(const unsigned short* __restrict__ hwb,
                                                  const float* __restrict__ dinv,
                                                  const int* __restrict__ cnt,
                                                  const int* __restrict__ off,
                                                  const int* __restrict__ es,
                                                  const float* __restrict__ bias2,
                                                  const float* __restrict__ wf1,
                                                  const float* __restrict__ bf1,
                                                  const float* __restrict__ wf2,
                                                  const float* __restrict__ bf2,
                                                  float* __restrict__ out) {
    __shared__ float hs[8][33];
    __shared__ float W1[512];
    __shared__ float B1[16];
    __shared__ float W2[16];
    int t = threadIdx.x;
    W1[t] = wf1[t];
    W1[t + 256] = wf1[t + 256];
    if (t < 16) { B1[t] = bf1[t]; W2[t] = wf2[t]; }

    int node0 = blockIdx.x * 8;
    int nl = t >> 5;            // local node 0..7
    int c = t & 31;
    int node = node0 + nl;
    float dn = dinv[node];
    float acc0 = b2f(hwb[(size_t)node * 32 + c]);
    float acc1 = 0.0f;
    const int* ep = es + off[node];
    int mp = cnt[node];
    for (int j = 0; j < mp; j += 8) {
        int4 e0 = *(const int4*)&ep[j];
        int4 e1 = *(const int4*)&ep[j + 4];
        float v0 = b2f(hwb[(size_t)e0.x * 32 + c]);
        float v1 = b2f(hwb[(size_t)e0.y * 32 + c]);
        float v2 = b2f(hwb[(size_t)e0.z * 32 + c]);
        float v3 = b2f(hwb[(size_t)e0.w * 32 + c]);
        float v4 = b2f(hwb[(size_t)e1.x * 32 + c]);
        float v5 = b2f(hwb[(size_t)e1.y * 32 + c]);
        float v6 = b2f(hwb[(size_t)e1.z * 32 + c]);
        float v7 = b2f(hwb[(size_t)e1.w * 32 + c]);
        acc0 += (v0 + v1) + (v2 + v3);
        acc1 += (v4 + v5) + (v6 + v7);
    }
    hs[nl][c] = fmaxf(fmaf(dn, acc0 + acc1, bias2[c]), 0.0f);
    __syncthreads();
    if (t < 128) {
        int nn = t >> 4, jj = t & 15;
        float s = B1[jj];
#pragma unroll
        for (int k = 0; k < 32; ++k) s += hs[nn][k] * W1[k * 16 + jj];
        float p = fmaxf(s, 0.0f) * W2[jj];
        p += __shfl_xor(p, 1);
        p += __shfl_xor(p, 2);
        p += __shfl_xor(p, 4);
        p += __shfl_xor(p, 8);
        if (jj == 0) out[node0 + nn] = p + bf2[0];
    }
}

// ---------------- host ----------------

extern "C" void kernel_launch(void* const* d_in, const int* in_sizes, int n_in,
                              void* d_out, int out_size, void* d_ws, size_t ws_size,
                              hipStream_t stream) {
    const float* x   = (const float*)d_in[0];
    const int*   ei  = (const int*)d_in[1];
    const float* w1  = (const float*)d_in[2];
    const float* b1  = (const float*)d_in[3];
    const float* w2  = (const float*)d_in[4];
    const float* b2  = (const float*)d_in[5];
    const float* wf1 = (const float*)d_in[6];
    const float* bf1 = (const float*)d_in[7];
    const float* wf2 = (const float*)d_in[8];
    const float* bf2 = (const float*)d_in[9];

    const int n = N_NODES;
    const int E = N_EDGES;
    const int* srcp = ei;        // edge_index[0]
    const int* dstp = ei + E;    // edge_index[1]

    char* p = (char*)d_ws;
    auto take = [&](size_t bytes) {
        char* r = p;
        p += (bytes + 255) & ~(size_t)255;
        return r;
    };
    float* dinv = (float*)take((size_t)(n + 1) * 4);   // +1 sentinel weight (=0)
    int*   cnt  = (int*)take((size_t)n * 4);
    int*   off  = (int*)take((size_t)n * 4);
    int*   gcnt = (int*)take((size_t)NSLOT * 4);
    int*   bsum = (int*)take(1024);
    int*   es   = (int*)take((size_t)ES_CAP * 4);
    unsigned* ebuf = (unsigned*)take((size_t)E * 4);   // no longer aliases hwb1
    unsigned short* hwb1 = (unsigned short*)take((size_t)(n + 1) * 64 * 2);
    unsigned short* hwb2 = (unsigned short*)take((size_t)(n + 1) * 32 * 2);

    // K1: hist || gemm1(raw, nt-x) — independent roles in one grid
    k_hist_gemm1<<<NPB + GEMM1_BLOCKS, 256, 0, stream>>>(dstp, gcnt, x, w1,
                                                         hwb1, hwb2, dinv, n);
    k_scanA<<<NSB, 1024, 0, stream>>>(gcnt, bsum, NSLOT);
    k_partition<<<NPB, 256, 0, stream>>>(srcp, dstp, gcnt, bsum, ebuf, E);
    k_bucket_csr<<<NBK, 256, 0, stream>>>(gcnt, bsum, ebuf, cnt, dinv, off, es, n);

    k_agg1_gemm2<<<n / 16, 256, 0, stream>>>(hwb1, dinv, cnt, off, es, b1, w2, hwb2);
    k_agg2_mlp<<<n / 8, 256, 0, stream>>>(hwb2, dinv, cnt, off, es, b2,
                                          wf1, bf1, wf2, bf2, (float*)d_out);
}

// Round 14
// 161.596 us; speedup vs baseline: 1.1310x; 1.1310x over previous
//
#include <hip/hip_runtime.h>
#include <cstdint>
#include <cstddef>

#define N_NODES 100000
#define N_EDGES 1600000

#define BKB   7                            // bucket = 128 nodes
#define BN    128
#define NBK   782                          // ceil(100000/128)
#define NPB   256                          // partition blocks
#define EPB   ((N_EDGES + NPB - 1) / NPB)  // 6250 edges per partition block
#define NSLOT (NBK * NPB)                  // 200192 (bucket-major: slot = b*NPB + bid)
#define NSB   ((NSLOT + 1023) / 1024)      // 196 scan blocks
#define ES_CAP (N_EDGES + NBK * 1024 + 64) // padded edge-list capacity
#define EB_CAP 2560                        // LDS stage cap per bucket (mean 2046, sd 45)

typedef __attribute__((ext_vector_type(8))) short bf16x8;
typedef __attribute__((ext_vector_type(4))) float f32x4;

__device__ __forceinline__ float b2f(unsigned short u) {
    return __uint_as_float(((unsigned)u) << 16);
}
__device__ __forceinline__ unsigned short f2b(float f) {
    unsigned x = __float_as_uint(f);
    return (unsigned short)((x + 0x7FFFu + ((x >> 16) & 1u)) >> 16);
}

// split 8 f32 -> bf16 hi (trunc) + bf16 lo (trunc of exact residual)
__device__ __forceinline__ void split8a(const float* f, bf16x8& hi, bf16x8& lo) {
#pragma unroll
    for (int j = 0; j < 8; ++j) {
        unsigned u = __float_as_uint(f[j]);
        hi[j] = (short)(u >> 16);
        float l = f[j] - __uint_as_float(u & 0xFFFF0000u);   // exact
        lo[j] = (short)(__float_as_uint(l) >> 16);
    }
}
__device__ __forceinline__ void split8(const float4& a0, const float4& a1,
                                       bf16x8& hi, bf16x8& lo) {
    float f[8] = {a0.x, a0.y, a0.z, a0.w, a1.x, a1.y, a1.z, a1.w};
    split8a(f, hi, lo);
}

// 256-wide exclusive prefix of bsum[0..NSB) into pe[256]; call with all 256 threads
__device__ __forceinline__ void bsum_excl(const int* __restrict__ bsum, int* pe) {
    int t = threadIdx.x;
    int v = (t < NSB) ? bsum[t] : 0;
    pe[t] = v;
    __syncthreads();
    for (int o = 1; o < 256; o <<= 1) {
        int a = (t >= o) ? pe[t - o] : 0;
        __syncthreads();
        pe[t] += a;
        __syncthreads();
    }
    pe[t] -= v;   // exclusive
    __syncthreads();
}

// ---------------- build: bucket partition with private sub-regions ----------------

// also zeroes the sentinel rows (row N_NODES) of both bf16 operand buffers (block 0)
__global__ __launch_bounds__(256) void k_hist(const int* __restrict__ dst,
                                              int* __restrict__ gcnt,
                                              unsigned short* __restrict__ hwb1,
                                              unsigned short* __restrict__ hwb2, int E) {
    __shared__ int lh[NBK];
    int t = threadIdx.x, bid = blockIdx.x;
    if (bid == 0) {
        if (t < 64) hwb1[(size_t)N_NODES * 64 + t] = 0;
        else if (t < 96) hwb2[(size_t)N_NODES * 32 + (t - 64)] = 0;
    }
    for (int i = t; i < NBK; i += 256) lh[i] = 0;
    __syncthreads();
    int e0 = bid * EPB, e1 = min(E, e0 + EPB);
    for (int e = e0 + t; e < e1; e += 256) atomicAdd(&lh[dst[e] >> BKB], 1);
    __syncthreads();
    for (int b = t; b < NBK; b += 256) gcnt[b * NPB + bid] = lh[b];
}

// per-scan-block local exclusive scan; bsum[blk] = block total
__global__ __launch_bounds__(1024) void k_scanA(int* __restrict__ g,
                                                int* __restrict__ bsum, int ntot) {
    __shared__ int s[1024];
    int t = threadIdx.x;
    int i = blockIdx.x * 1024 + t;
    int v = (i < ntot) ? g[i] : 0;
    s[t] = v;
    __syncthreads();
    for (int o = 1; o < 1024; o <<= 1) {
        int a = (t >= o) ? s[t - o] : 0;
        __syncthreads();
        s[t] += a;
        __syncthreads();
    }
    if (i < ntot) g[i] = s[t] - v;
    if (t == 1023) bsum[blockIdx.x] = s[1023];
}

__global__ __launch_bounds__(256) void k_partition(const int* __restrict__ src,
                                                   const int* __restrict__ dst,
                                                   const int* __restrict__ g,
                                                   const int* __restrict__ bsum,
                                                   unsigned* __restrict__ ebuf, int E) {
    __shared__ int lcur[NBK];
    __shared__ int pe[256];
    int t = threadIdx.x, bid = blockIdx.x;
    bsum_excl(bsum, pe);
    for (int b = t; b < NBK; b += 256) {
        int slot = b * NPB + bid;
        lcur[b] = g[slot] + pe[slot >> 10];
    }
    __syncthreads();
    int e0 = bid * EPB, e1 = min(E, e0 + EPB);
    for (int e = e0 + t; e < e1; e += 256) {
        int d = dst[e];
        int b = d >> BKB;
        int p = atomicAdd(&lcur[b], 1);
        ebuf[p] = (unsigned)src[e] | ((unsigned)(d & (BN - 1)) << 20);
    }
}

// one block per 128-node bucket: stage edges in LDS, count/scan/place -> 8-padded CSR
__global__ __launch_bounds__(256) void k_bucket_csr(const int* __restrict__ g,
                                                    const int* __restrict__ bsum,
                                                    const unsigned* __restrict__ ebuf,
                                                    int* __restrict__ cnt,
                                                    float* __restrict__ dinv,
                                                    int* __restrict__ off,
                                                    int* __restrict__ es, int n) {
    __shared__ unsigned eb[EB_CAP];
    __shared__ int lc[BN];
    __shared__ int ss[BN];
    __shared__ int lo[BN];
    __shared__ int lcur[BN];
    __shared__ int pe[256];
    int b = blockIdx.x, t = threadIdx.x;
    bsum_excl(bsum, pe);
    int s0 = b * NPB;
    int rstart = g[s0] + pe[s0 >> 10];
    int rend;
    if (b == NBK - 1) rend = N_EDGES;
    else { int s1 = (b + 1) * NPB; rend = g[s1] + pe[s1 >> 10]; }
    int m = rend - rstart;
    int ms = min(m, EB_CAP);
    int wstart = ((rstart + 7) & ~7) + b * 1024;   // 8-aligned private write region
    if (t < BN) lc[t] = 0;
    for (int i = t; i < ms; i += 256) eb[i] = ebuf[rstart + i];
    __syncthreads();
    for (int e = t; e < m; e += 256) {
        unsigned u = (e < ms) ? eb[e] : ebuf[rstart + e];
        atomicAdd(&lc[(int)(u >> 20)], 1);
    }
    __syncthreads();
    int v = 0, vp = 0;
    if (t < BN) {
        v = lc[t];               // real degree
        vp = (v + 7) & ~7;       // padded to multiple of 8
        ss[t] = vp;
    }
    __syncthreads();
    for (int o = 1; o < BN; o <<= 1) {
        int a = (t >= o && t < BN) ? ss[t - o] : 0;
        __syncthreads();
        if (t < BN) ss[t] += a;
        __syncthreads();
    }
    if (t < BN) {
        lo[t] = ss[t] - vp;
        lcur[t] = 0;
        int node = b * BN + t;
        if (node < n) {
            cnt[node] = vp;
            dinv[node] = rsqrtf((float)v + 1.0f);
            off[node] = wstart + lo[t];
        }
    }
    __syncthreads();
    for (int e = t; e < m; e += 256) {
        unsigned u = (e < ms) ? eb[e] : ebuf[rstart + e];
        int l = (int)(u >> 20);
        int p = atomicAdd(&lcur[l], 1);
        es[wstart + lo[l] + p] = (int)(u & 0xFFFFFu);
    }
    if (t < BN)
        for (int q = v; q < vp; ++q) es[wstart + lo[t] + q] = N_NODES;
}

// ---------------- GEMM1 (MFMA hi/lo): hwb1 = bf16( dinv * (x[M,256] @ w1[256,64]) ) ----

__global__ __launch_bounds__(256) void k_gemm1_mfma(const float* __restrict__ x,
                                                    const float* __restrict__ w,
                                                    const float* __restrict__ dinv,
                                                    unsigned short* __restrict__ out, int M) {
    __shared__ unsigned short Bhi[32 * 64 * 8];   // 32 KB
    __shared__ unsigned short Blo[32 * 64 * 8];   // 32 KB
    int t = threadIdx.x;
    int wave = t >> 6, lane = t & 63;

    {
        int c = t & 63;
        int kg0 = t >> 6;
#pragma unroll
        for (int i = 0; i < 8; ++i) {
            int kgrp = kg0 + i * 4;
            bf16x8 h8, l8;
#pragma unroll
            for (int j = 0; j < 8; ++j) {
                float f = w[(size_t)(kgrp * 8 + j) * 64 + c];
                unsigned u = __float_as_uint(f);
                h8[j] = (short)(u >> 16);
                float l = f - __uint_as_float(u & 0xFFFF0000u);
                l8[j] = (short)(__float_as_uint(l) >> 16);
            }
            *(bf16x8*)&Bhi[(kgrp * 64 + c) * 8] = h8;
            *(bf16x8*)&Blo[(kgrp * 64 + c) * 8] = l8;
        }
    }
    __syncthreads();

    int row0w = blockIdx.x * 64 + wave * 16;
    int r = row0w + (lane & 15); if (r >= M) r = M - 1;
    const float* xr = x + (size_t)r * 256 + (lane >> 4) * 8;

    f32x4 acc[4] = {{0.f,0.f,0.f,0.f},{0.f,0.f,0.f,0.f},{0.f,0.f,0.f,0.f},{0.f,0.f,0.f,0.f}};

#pragma unroll
    for (int kf = 0; kf < 8; ++kf) {
        float4 a0 = *(const float4*)(xr + kf * 32);
        float4 a1 = *(const float4*)(xr + kf * 32 + 4);
        bf16x8 ahi, alo;
        split8(a0, a1, ahi, alo);
        int kgrpR = kf * 4 + (lane >> 4);
#pragma unroll
        for (int cf = 0; cf < 4; ++cf) {
            bf16x8 bhi = *(const bf16x8*)&Bhi[(kgrpR * 64 + cf * 16 + (lane & 15)) * 8];
            bf16x8 blo = *(const bf16x8*)&Blo[(kgrpR * 64 + cf * 16 + (lane & 15)) * 8];
            acc[cf] = __builtin_amdgcn_mfma_f32_16x16x32_bf16(ahi, bhi, acc[cf], 0, 0, 0);
            acc[cf] = __builtin_amdgcn_mfma_f32_16x16x32_bf16(ahi, blo, acc[cf], 0, 0, 0);
            acc[cf] = __builtin_amdgcn_mfma_f32_16x16x32_bf16(alo, bhi, acc[cf], 0, 0, 0);
        }
    }

#pragma unroll
    for (int j = 0; j < 4; ++j) {
        int rr = row0w + (lane >> 4) * 4 + j;
        if (rr < M) {
            float s = dinv[rr];
#pragma unroll
            for (int cf = 0; cf < 4; ++cf)
                out[(size_t)rr * 64 + cf * 16 + (lane & 15)] = f2b(acc[cf][j] * s);
        }
    }
}

// ---------------- fused agg1 + GEMM2: hwb2 = bf16( dinv * (relu-agg(hwb1) @ w2) ) ------
// block = 16 nodes (4 waves x 4 interleaved nodes). Gather: lane = channel, 2B gathers.
// MFMA phase: waves 0/1 compute 16x32 = h1tile @ w2 (hi/lo split), write bf16.

__global__ __launch_bounds__(256) void k_agg1_gemm2(const unsigned short* __restrict__ hwb,
                                                    const float* __restrict__ dinv,
                                                    const int* __restrict__ cnt,
                                                    const int* __restrict__ off,
                                                    const int* __restrict__ es,
                                                    const float* __restrict__ bias,
                                                    const float* __restrict__ w2,
                                                    unsigned short* __restrict__ out) {
    __shared__ float hs[16][68];     // 16 h1 rows, padded (stride 68 -> 2-way banks)
    int t = threadIdx.x;
    int wv = t >> 6, lane = t & 63;
    int node0 = blockIdx.x * 16;
    float bl = bias[lane];

    float dn[4], a0[4], a1[4];
    const int* ep[4];
    int mp[4];
#pragma unroll
    for (int i = 0; i < 4; ++i) {
        int node = node0 + wv * 4 + i;
        dn[i] = dinv[node];
        a0[i] = b2f(hwb[(size_t)node * 64 + lane]);   // self (pre-scaled)
        a1[i] = 0.0f;
        ep[i] = es + off[node];
        mp[i] = cnt[node];
    }
    int mmax = max(max(mp[0], mp[1]), max(mp[2], mp[3]));
    for (int j = 0; j < mmax; j += 8) {
#pragma unroll
        for (int i = 0; i < 4; ++i) {
            if (j < mp[i]) {   // wave-uniform
                int4 e0 = *(const int4*)&ep[i][j];
                int4 e1 = *(const int4*)&ep[i][j + 4];
                float v0 = b2f(hwb[(size_t)e0.x * 64 + lane]);
                float v1 = b2f(hwb[(size_t)e0.y * 64 + lane]);
                float v2 = b2f(hwb[(size_t)e0.z * 64 + lane]);
                float v3 = b2f(hwb[(size_t)e0.w * 64 + lane]);
                float v4 = b2f(hwb[(size_t)e1.x * 64 + lane]);
                float v5 = b2f(hwb[(size_t)e1.y * 64 + lane]);
                float v6 = b2f(hwb[(size_t)e1.z * 64 + lane]);
                float v7 = b2f(hwb[(size_t)e1.w * 64 + lane]);
                a0[i] += (v0 + v1) + (v2 + v3);
                a1[i] += (v4 + v5) + (v6 + v7);
            }
        }
    }
#pragma unroll
    for (int i = 0; i < 4; ++i)
        hs[wv * 4 + i][lane] = fmaxf(fmaf(dn[i], a0[i] + a1[i], bl), 0.0f);
    __syncthreads();

    if (wv < 2) {
        int colbase = wv * 16;
        int r = lane & 15;           // A row / B col / C col
        int kg = lane >> 4;          // k-group 0..3
        f32x4 acc = {0.f, 0.f, 0.f, 0.f};
#pragma unroll
        for (int ks = 0; ks < 2; ++ks) {
            float a[8], b[8];
#pragma unroll
            for (int j = 0; j < 8; ++j) {
                int k = ks * 32 + kg * 8 + j;
                a[j] = hs[r][k];
                b[j] = w2[(size_t)k * 32 + colbase + r];
            }
            bf16x8 ahi, alo, bhi, blo;
            split8a(a, ahi, alo);
            split8a(b, bhi, blo);
            acc = __builtin_amdgcn_mfma_f32_16x16x32_bf16(ahi, bhi, acc, 0, 0, 0);
            acc = __builtin_amdgcn_mfma_f32_16x16x32_bf16(ahi, blo, acc, 0, 0, 0);
            acc = __builtin_amdgcn_mfma_f32_16x16x32_bf16(alo, bhi, acc, 0, 0, 0);
        }
#pragma unroll
        for (int reg = 0; reg < 4; ++reg) {
            int row = kg * 4 + reg;
            int nd = node0 + row;
            out[(size_t)nd * 32 + colbase + r] = f2b(acc[reg] * dinv[nd]);
        }
    }
}

// ---------------- agg layer 2 + fused MLP head ------------------

__global__ __launch_bounds__(256) void k_agg2_mlp(const unsigned short* __restrict__ hwb,
                                                  const float* __restrict__ dinv,
                                                  const int* __restrict__ cnt,
                                                  const int* __restrict__ off,
                                                  const int* __restrict__ es,
                                                  const float* __restrict__ bias2,
                                                  const float* __restrict__ wf1,
                                                  const float* __restrict__ bf1,
                                                  const float* __restrict__ wf2,
                                                  const float* __restrict__ bf2,
                                                  float* __restrict__ out) {
    __shared__ float hs[8][33];
    __shared__ float W1[512];
    __shared__ float B1[16];
    __shared__ float W2[16];
    int t = threadIdx.x;
    W1[t] = wf1[t];
    W1[t + 256] = wf1[t + 256];
    if (t < 16) { B1[t] = bf1[t]; W2[t] = wf2[t]; }

    int node0 = blockIdx.x * 8;
    int nl = t >> 5;            // local node 0..7
    int c = t & 31;
    int node = node0 + nl;
    float dn = dinv[node];
    float acc0 = b2f(hwb[(size_t)node * 32 + c]);
    float acc1 = 0.0f;
    const int* ep = es + off[node];
    int mp = cnt[node];
    for (int j = 0; j < mp; j += 8) {
        int4 e0 = *(const int4*)&ep[j];
        int4 e1 = *(const int4*)&ep[j + 4];
        float v0 = b2f(hwb[(size_t)e0.x * 32 + c]);
        float v1 = b2f(hwb[(size_t)e0.y * 32 + c]);
        float v2 = b2f(hwb[(size_t)e0.z * 32 + c]);
        float v3 = b2f(hwb[(size_t)e0.w * 32 + c]);
        float v4 = b2f(hwb[(size_t)e1.x * 32 + c]);
        float v5 = b2f(hwb[(size_t)e1.y * 32 + c]);
        float v6 = b2f(hwb[(size_t)e1.z * 32 + c]);
        float v7 = b2f(hwb[(size_t)e1.w * 32 + c]);
        acc0 += (v0 + v1) + (v2 + v3);
        acc1 += (v4 + v5) + (v6 + v7);
    }
    hs[nl][c] = fmaxf(fmaf(dn, acc0 + acc1, bias2[c]), 0.0f);
    __syncthreads();
    if (t < 128) {
        int nn = t >> 4, jj = t & 15;
        float s = B1[jj];
#pragma unroll
        for (int k = 0; k < 32; ++k) s += hs[nn][k] * W1[k * 16 + jj];
        float p = fmaxf(s, 0.0f) * W2[jj];
        p += __shfl_xor(p, 1);
        p += __shfl_xor(p, 2);
        p += __shfl_xor(p, 4);
        p += __shfl_xor(p, 8);
        if (jj == 0) out[node0 + nn] = p + bf2[0];
    }
}

// ---------------- host ----------------

extern "C" void kernel_launch(void* const* d_in, const int* in_sizes, int n_in,
                              void* d_out, int out_size, void* d_ws, size_t ws_size,
                              hipStream_t stream) {
    const float* x   = (const float*)d_in[0];
    const int*   ei  = (const int*)d_in[1];
    const float* w1  = (const float*)d_in[2];
    const float* b1  = (const float*)d_in[3];
    const float* w2  = (const float*)d_in[4];
    const float* b2  = (const float*)d_in[5];
    const float* wf1 = (const float*)d_in[6];
    const float* bf1 = (const float*)d_in[7];
    const float* wf2 = (const float*)d_in[8];
    const float* bf2 = (const float*)d_in[9];

    const int n = N_NODES;
    const int E = N_EDGES;
    const int* srcp = ei;        // edge_index[0]
    const int* dstp = ei + E;    // edge_index[1]

    char* p = (char*)d_ws;
    auto take = [&](size_t bytes) {
        char* r = p;
        p += (bytes + 255) & ~(size_t)255;
        return r;
    };
    float* dinv = (float*)take((size_t)n * 4);
    int*   cnt  = (int*)take((size_t)n * 4);
    int*   off  = (int*)take((size_t)n * 4);
    int*   gcnt = (int*)take((size_t)NSLOT * 4);
    int*   bsum = (int*)take(1024);
    int*   es   = (int*)take((size_t)ES_CAP * 4);
    unsigned short* hwb1 = (unsigned short*)take((size_t)(n + 1) * 64 * 2);  // aliases ebuf
    unsigned short* hwb2 = (unsigned short*)take((size_t)(n + 1) * 32 * 2);
    unsigned* ebuf = (unsigned*)hwb1;   // 6.4MB, consumed by k_bucket_csr before gemm1

    // build per-node padded CSR (bucketed two-phase, no global atomics)
    k_hist<<<NPB, 256, 0, stream>>>(dstp, gcnt, hwb1, hwb2, E);
    k_scanA<<<NSB, 1024, 0, stream>>>(gcnt, bsum, NSLOT);
    k_partition<<<NPB, 256, 0, stream>>>(srcp, dstp, gcnt, bsum, ebuf, E);
    k_bucket_csr<<<NBK, 256, 0, stream>>>(gcnt, bsum, ebuf, cnt, dinv, off, es, n);

    // GNN layers
    k_gemm1_mfma<<<(n + 63) / 64, 256, 0, stream>>>(x, w1, dinv, hwb1, n);
    k_agg1_gemm2<<<n / 16, 256, 0, stream>>>(hwb1, dinv, cnt, off, es, b1, w2, hwb2);
    k_agg2_mlp<<<n / 8, 256, 0, stream>>>(hwb2, dinv, cnt, off, es, b2,
                                          wf1, bf1, wf2, bf2, (float*)d_out);
}